// Round 12
// baseline (1044.811 us; speedup 1.0000x reference)
//
#include <hip/hip_runtime.h>

#define NTHR 256
#define NBLK 1024              // B / NTHR; block == one 256-slot chunk
#define NCHUNK 1024            // 256-slot chunks (cnt entries)

typedef unsigned long long u64;
typedef float v2 __attribute__((ext_vector_type(2)));

// ---------------------------------------------------------------------------
// MLP + hysteresis. Packed-FP32 pairs over output neurons (j, j+1).
// Per-ELEMENT arithmetic byte-identical to the validated scalar version.
// ---------------------------------------------------------------------------
__device__ __forceinline__ void mlp_update(
    const float lin, const float x, const float isOn,
    const float* __restrict__ W1, const float* __restrict__ b1,
    const float* __restrict__ W2, const float* __restrict__ b2,
    const float* __restrict__ W3, const float* __restrict__ b3,
    float& x_new, float& isOn_new, bool& off)
{
    off = (isOn <= 0.5f);

    const v2* __restrict__ W1r0 = (const v2*)W1;          // row 0 (lin weights)
    const v2* __restrict__ W1r1 = (const v2*)(W1 + 32);   // row 1 (x weights)
    const v2* __restrict__ b1p  = (const v2*)b1;
    const v2* __restrict__ b2p  = (const v2*)b2;

    const v2 linv = { lin, lin };
    const v2 xv   = { x, x };
    const v2 zero = { 0.0f, 0.0f };

    v2 h1v[16];
#pragma unroll
    for (int jp = 0; jp < 16; ++jp) {
        v2 a = linv * W1r0[jp];                           // v_pk_mul_f32
        a = __builtin_elementwise_fma(xv, W1r1[jp], a);   // v_pk_fma_f32
        a = a + b1p[jp];                                  // v_pk_add_f32
        h1v[jp] = __builtin_elementwise_max(a, zero);     // v_pk_max_f32
    }

    float o = 0.0f;
#pragma unroll
    for (int jp = 0; jp < 16; ++jp) {
        v2 a = { 0.0f, 0.0f };
        const v2* __restrict__ w2col = (const v2*)(W2) + jp;  // stride 16 v2/row
#pragma unroll
        for (int kp = 0; kp < 16; ++kp) {
            a = __builtin_elementwise_fma(h1v[kp].xx, w2col[(2 * kp) * 16], a);
            a = __builtin_elementwise_fma(h1v[kp].yy, w2col[(2 * kp + 1) * 16], a);
        }
        a = a + b2p[jp];
        const float ax = fmaxf(a.x, 0.0f);
        const float ay = fmaxf(a.y, 0.0f);
        o = fmaf(ax, W3[2 * jp], o);
        o = fmaf(ay, W3[2 * jp + 1], o);
    }
    o += b3[0];

    const float plant = o * 10.0f;
    const float tm = x - plant;
    x_new = off ? tm : tm + 10.0f;
    isOn_new = off ? ((x_new <= 66.0f) ? 1.0f : isOn)
                   : ((x_new > 78.0f) ? 0.0f : isOn);
}

// ---------------------------------------------------------------------------
// One kernel per simulation step; 1024 blocks x 256 thr, 1 elem/thread.
// Producer stores CHUNK-COMPACTED payload: within chunk c, off rows (in slot
// order) occupy [c*256, c*256+cnt_c), on rows follow. Consumer therefore
// needs only the cnt scan + LDS binary search: src = b*256 + rem (off) or
// b*256 + cnt_b + rem (on). No masks, no nth_set_bit, one scattered load.
//   mode 0: first step  — x from input, isOn=0, no pull
//   mode 1: middle step — pull permuted state, write traj row t-1, compute
//   mode 2: final pull  — pull only, write last traj row
// ---------------------------------------------------------------------------
__global__ __launch_bounds__(NTHR, 4) void fused_kernel(
    const float2* __restrict__ inp,
    const float* __restrict__ W1, const float* __restrict__ b1,
    const float* __restrict__ W2, const float* __restrict__ b2,
    const float* __restrict__ W3, const float* __restrict__ b3,
    const float2* __restrict__ payPrev, const unsigned* __restrict__ cntPrev,
    float2* __restrict__ payNew, unsigned* __restrict__ cntNew,
    float* __restrict__ outRow,
    int mode)
{
    const int tid  = threadIdx.x;
    const int lane = tid & 63;
    const int wv   = tid >> 6;
    const int i    = blockIdx.x * NTHR + tid;

    __shared__ unsigned bp[NCHUNK];
    __shared__ unsigned wsum[NTHR / 64];
    __shared__ unsigned wOff[NTHR / 64];

    float x, isOn;
    if (mode == 0) {
        const float2 iv = inp[i];
        x = iv.y; isOn = 0.0f;
    } else {
        // ---- cnt scan (verified R7 structure): 1024 counts, uint4/thread ----
        const uint4 cc = ((const uint4*)cntPrev)[tid];
        const unsigned s = cc.x + cc.y + cc.z + cc.w;
        unsigned inc = s;
#pragma unroll
        for (int d = 1; d < 64; d <<= 1) {
            unsigned v = __shfl_up(inc, d);
            if (lane >= d) inc += v;
        }
        if (lane == 63) wsum[wv] = inc;
        __syncthreads();
        unsigned T = 0, wexcl = 0;
#pragma unroll
        for (int w = 0; w < NTHR / 64; ++w) {
            T += wsum[w];
            if (w < wv) wexcl += wsum[w];
        }
        unsigned r0 = wexcl + inc - s;
        const unsigned base = tid * 4;
        bp[base]     = r0; r0 += cc.x;
        bp[base + 1] = r0; r0 += cc.y;
        bp[base + 2] = r0; r0 += cc.z;
        bp[base + 3] = r0;
        __syncthreads();

        // ---- chunk search (verified structure), then direct payload index ----
        int src;
        if ((unsigned)i < T) {
            const unsigned r = (unsigned)i;
            int b = 0;
#pragma unroll
            for (int st = NCHUNK / 2; st; st >>= 1) {
                const int nb = b + st;
                if (nb < NCHUNK && bp[nb] <= r) b = nb;
            }
            src = b * NTHR + (int)(r - bp[b]);                 // off side
        } else {
            const unsigned q = (unsigned)i - T;
            int b = 0;
#pragma unroll
            for (int st = NCHUNK / 2; st; st >>= 1) {
                const int nb = b + st;
                if (nb < NCHUNK && ((unsigned)NTHR * (unsigned)nb - bp[nb]) <= q) b = nb;
            }
            const unsigned bpb = bp[b];
            const unsigned rem = q - ((unsigned)NTHR * (unsigned)b - bpb);
            const unsigned bpn = (b == NCHUNK - 1) ? T : bp[b + 1];
            const unsigned cntb = bpn - bpb;
            src = b * NTHR + (int)(cntb + rem);                // on side
        }

        const float2 sv = payPrev[src];
        x = sv.x; isOn = sv.y;
        outRow[i] = x;
        if (mode == 2) return;
    }

    const float lin = inp[i].x;
    float x_new, isOn_new;
    bool off;
    mlp_update(lin, x, isOn, W1, b1, W2, b2, W3, b3, x_new, isOn_new, off);

    // ---- producer: chunk-local compaction (off rows first, then on rows) ----
    const u64 bm = __ballot(off);
    if (lane == 0) wOff[wv] = (unsigned)__popcll(bm);
    __syncthreads();
    unsigned cntb = 0, woexcl = 0;
#pragma unroll
    for (int w = 0; w < NTHR / 64; ++w) {
        cntb += wOff[w];
        if (w < wv) woexcl += wOff[w];
    }
    const unsigned laneRank = (unsigned)__popcll(bm & ((1ull << lane) - 1ull));
    const unsigned offRank = woexcl + laneRank;
    const unsigned pos = off ? offRank : cntb + ((unsigned)tid - offRank);
    payNew[blockIdx.x * NTHR + pos] = make_float2(x_new, isOn_new);
    if (tid == 0) cntNew[blockIdx.x] = cntb;
}

// ---------------------------------------------------------------------------
extern "C" void kernel_launch(void* const* d_in, const int* in_sizes, int n_in,
                              void* d_out, int out_size, void* d_ws, size_t ws_size,
                              hipStream_t stream)
{
    const float2* inp = (const float2*)d_in[0];
    const float* W1 = (const float*)d_in[1];
    const float* b1 = (const float*)d_in[2];
    const float* W2 = (const float*)d_in[3];
    const float* b2 = (const float*)d_in[4];
    const float* W3 = (const float*)d_in[5];
    const float* b3 = (const float*)d_in[6];
    float* out = (float*)d_out;

    const int B = in_sizes[0] / 2;          // 262144
    const int nsteps = out_size / B;        // 40

    float2*   pay0 = (float2*)d_ws;
    float2*   pay1 = pay0 + B;
    unsigned* cnt0 = (unsigned*)(pay1 + B);
    unsigned* cnt1 = cnt0 + NCHUNK;

    // step 0: no pull
    fused_kernel<<<NBLK, NTHR, 0, stream>>>(inp, W1, b1, W2, b2, W3, b3,
                                            pay0, cnt0, pay0, cnt0,
                                            nullptr, 0);
    // steps 1..nsteps-1: pull prev (writes traj row t-1) + compute step t
    for (int t = 1; t < nsteps; ++t) {
        const bool odd = (t & 1);
        const float2*   payP = odd ? pay0 : pay1;
        const unsigned* cntP = odd ? cnt0 : cnt1;
        float2*   payN = odd ? pay1 : pay0;
        unsigned* cntN = odd ? cnt1 : cnt0;
        fused_kernel<<<NBLK, NTHR, 0, stream>>>(inp, W1, b1, W2, b2, W3, b3,
                                                payP, cntP, payN, cntN,
                                                out + (size_t)(t - 1) * B, 1);
    }
    // final pull-only: traj row nsteps-1
    {
        const bool odd = (nsteps & 1);
        const float2*   payP = odd ? pay0 : pay1;
        const unsigned* cntP = odd ? cnt0 : cnt1;
        fused_kernel<<<NBLK, NTHR, 0, stream>>>(inp, W1, b1, W2, b2, W3, b3,
                                                payP, cntP, pay0, cnt0,
                                                out + (size_t)(nsteps - 1) * B, 2);
    }
}

// Round 13
// 398.764 us; speedup vs baseline: 2.6201x; 2.6201x over previous
//
#include <hip/hip_runtime.h>

#define NTHR 256
#define NBLK 1024              // B / NTHR
#define NCHUNK 1024            // 256-slot chunks (cnt/bp entries)

typedef unsigned long long u64;
typedef float v2 __attribute__((ext_vector_type(2)));

// ---------------------------------------------------------------------------
// index of the (n+1)-th set bit of m (n 0-based), 6-step binary search
__device__ __forceinline__ int nth_set_bit(u64 m, unsigned n) {
    int pos = 0;
#pragma unroll
    for (int st = 32; st; st >>= 1) {
        u64 low = (1ull << (pos + st)) - 1ull;
        if ((unsigned)__popcll(m & low) <= n) pos += st;
    }
    return pos;
}

// ---------------------------------------------------------------------------
// MLP + hysteresis. Packed-FP32 pairs over output neurons (j, j+1).
// Per-ELEMENT arithmetic byte-identical to the validated scalar version.
// ---------------------------------------------------------------------------
__device__ __forceinline__ void mlp_update(
    const float lin, const float x, const float isOn,
    const float* __restrict__ W1, const float* __restrict__ b1,
    const float* __restrict__ W2, const float* __restrict__ b2,
    const float* __restrict__ W3, const float* __restrict__ b3,
    float& x_new, float& isOn_new, bool& off)
{
    off = (isOn <= 0.5f);

    const v2* __restrict__ W1r0 = (const v2*)W1;          // row 0 (lin weights)
    const v2* __restrict__ W1r1 = (const v2*)(W1 + 32);   // row 1 (x weights)
    const v2* __restrict__ b1p  = (const v2*)b1;
    const v2* __restrict__ b2p  = (const v2*)b2;

    const v2 linv = { lin, lin };
    const v2 xv   = { x, x };
    const v2 zero = { 0.0f, 0.0f };

    v2 h1v[16];
#pragma unroll
    for (int jp = 0; jp < 16; ++jp) {
        v2 a = linv * W1r0[jp];                           // v_pk_mul_f32
        a = __builtin_elementwise_fma(xv, W1r1[jp], a);   // v_pk_fma_f32
        a = a + b1p[jp];                                  // v_pk_add_f32
        h1v[jp] = __builtin_elementwise_max(a, zero);     // v_pk_max_f32
    }

    float o = 0.0f;
#pragma unroll
    for (int jp = 0; jp < 16; ++jp) {
        v2 a = { 0.0f, 0.0f };
        const v2* __restrict__ w2col = (const v2*)(W2) + jp;  // stride 16 v2/row
#pragma unroll
        for (int kp = 0; kp < 16; ++kp) {
            a = __builtin_elementwise_fma(h1v[kp].xx, w2col[(2 * kp) * 16], a);
            a = __builtin_elementwise_fma(h1v[kp].yy, w2col[(2 * kp + 1) * 16], a);
        }
        a = a + b2p[jp];
        const float ax = fmaxf(a.x, 0.0f);
        const float ay = fmaxf(a.y, 0.0f);
        o = fmaf(ax, W3[2 * jp], o);
        o = fmaf(ay, W3[2 * jp + 1], o);
    }
    o += b3[0];

    const float plant = o * 10.0f;
    const float tm = x - plant;
    x_new = off ? tm : tm + 10.0f;
    isOn_new = off ? ((x_new <= 66.0f) ? 1.0f : isOn)
                   : ((x_new > 78.0f) ? 0.0f : isOn);
}

// ---------------------------------------------------------------------------
// One kernel per simulation step (R7 structure). Consumer chunk search is now
// wave-uniform (LDS-broadcast binary search on the wave's first off/on rank)
// + a short per-lane forward walk with a bp[1024]=T sentinel. Masks /
// nth_set_bit / producer tail / buffer layout are R7 verbatim.
//   mode 0: first step  — x from input, isOn=0, no pull
//   mode 1: middle step — pull permuted state, write traj row t-1, compute
//   mode 2: final pull  — pull only, write last traj row
// ---------------------------------------------------------------------------
__global__ __launch_bounds__(NTHR, 4) void fused_kernel(
    const float2* __restrict__ inp,
    const float* __restrict__ W1, const float* __restrict__ b1,
    const float* __restrict__ W2, const float* __restrict__ b2,
    const float* __restrict__ W3, const float* __restrict__ b3,
    const float2* __restrict__ stPrev, const unsigned* __restrict__ cntPrev,
    const u64* __restrict__ mskPrev,
    float2* __restrict__ stNew, unsigned* __restrict__ cntNew,
    u64* __restrict__ mskNew,
    float* __restrict__ outRow,
    int mode)
{
    const int tid  = threadIdx.x;
    const int lane = tid & 63;
    const int wv   = tid >> 6;
    const int i    = blockIdx.x * NTHR + tid;

    float x, isOn;
    if (mode == 0) {
        const float2 iv = inp[i];
        x = iv.y; isOn = 0.0f;
    } else {
        __shared__ unsigned bp[NCHUNK + 1];     // +1: sentinel bp[1024] = T
        __shared__ unsigned wsum[NTHR / 64];
        // ---- cnt scan (R7 verbatim): 1024 counts, uint4/thread ----
        const uint4 cc = ((const uint4*)cntPrev)[tid];
        const unsigned s = cc.x + cc.y + cc.z + cc.w;
        unsigned inc = s;
#pragma unroll
        for (int d = 1; d < 64; d <<= 1) {
            unsigned v = __shfl_up(inc, d);
            if (lane >= d) inc += v;
        }
        if (lane == 63) wsum[wv] = inc;
        __syncthreads();
        unsigned T = 0, wexcl = 0;
#pragma unroll
        for (int w = 0; w < NTHR / 64; ++w) {
            T += wsum[w];
            if (w < wv) wexcl += wsum[w];
        }
        unsigned r0 = wexcl + inc - s;
        const unsigned base = tid * 4;
        bp[base]     = r0; r0 += cc.x;
        bp[base + 1] = r0; r0 += cc.y;
        bp[base + 2] = r0; r0 += cc.z;
        bp[base + 3] = r0;
        if (tid == 0) bp[NCHUNK] = T;           // sentinel
        __syncthreads();

        // ---- wave-uniform searches (all lanes read the SAME bp address) ----
        const unsigned iw0 = (unsigned)(blockIdx.x * NTHR + (tid & ~63));
        const unsigned kOff = iw0;                              // first off-rank
        const unsigned kOn  = (iw0 >= T) ? (iw0 - T) : 0u;      // first on-rank
        int bOff = 0, bOn = 0;
#pragma unroll
        for (int st = NCHUNK / 2; st; st >>= 1) {
            const int n1 = bOff + st;
            if (n1 < NCHUNK && bp[n1] <= kOff) bOff = n1;
            const int n2 = bOn + st;
            if (n2 < NCHUNK && (256u * (unsigned)n2 - bp[n2]) <= kOn) bOn = n2;
        }

        // ---- per-lane short walk + mask select (R7 mask math verbatim) ----
        int src;
        if ((unsigned)i < T) {
            const unsigned r = (unsigned)i;
            int b = bOff;
            while (bp[b + 1] <= r) ++b;          // expected <= 2 iters
            const unsigned rr = r - bp[b];
            const u64 m0 = mskPrev[4 * b],     m1 = mskPrev[4 * b + 1];
            const u64 m2 = mskPrev[4 * b + 2], m3 = mskPrev[4 * b + 3];
            const unsigned p0 = __popcll(m0), p1 = __popcll(m1), p2 = __popcll(m2);
            int w; u64 m; unsigned nn;
            if (rr < p0)                { w = 0; m = m0; nn = rr; }
            else if (rr < p0 + p1)      { w = 1; m = m1; nn = rr - p0; }
            else if (rr < p0 + p1 + p2) { w = 2; m = m2; nn = rr - p0 - p1; }
            else                        { w = 3; m = m3; nn = rr - p0 - p1 - p2; }
            src = b * NTHR + w * 64 + nth_set_bit(m, nn);
        } else {
            const unsigned q = (unsigned)i - T;
            int b = bOn;
            while (256u * (unsigned)(b + 1) - bp[b + 1] <= q) ++b;
            const unsigned qq = q - (256u * (unsigned)b - bp[b]);
            const u64 m0 = ~mskPrev[4 * b],     m1 = ~mskPrev[4 * b + 1];
            const u64 m2 = ~mskPrev[4 * b + 2], m3 = ~mskPrev[4 * b + 3];
            const unsigned p0 = __popcll(m0), p1 = __popcll(m1), p2 = __popcll(m2);
            int w; u64 m; unsigned nn;
            if (qq < p0)                { w = 0; m = m0; nn = qq; }
            else if (qq < p0 + p1)      { w = 1; m = m1; nn = qq - p0; }
            else if (qq < p0 + p1 + p2) { w = 2; m = m2; nn = qq - p0 - p1; }
            else                        { w = 3; m = m3; nn = qq - p0 - p1 - p2; }
            src = b * NTHR + w * 64 + nth_set_bit(m, nn);
        }

        const float2 sv = stPrev[src];
        x = sv.x; isOn = sv.y;
        outRow[i] = x;
        if (mode == 2) return;
    }

    const float lin = inp[i].x;
    float x_new, isOn_new;
    bool off;
    mlp_update(lin, x, isOn, W1, b1, W2, b2, W3, b3, x_new, isOn_new, off);

    stNew[i] = make_float2(x_new, isOn_new);

    // ---- producer tail: R7 verbatim (coalesced stores, masks, counts) ----
    const u64 bm = __ballot(off);
    __shared__ unsigned wOff[NTHR / 64];
    if (lane == 0) { mskNew[i >> 6] = bm; wOff[wv] = (unsigned)__popcll(bm); }
    __syncthreads();
    if (tid == 0) {
        unsigned ssum = 0;
#pragma unroll
        for (int w2 = 0; w2 < NTHR / 64; ++w2) ssum += wOff[w2];
        cntNew[blockIdx.x] = ssum;
    }
}

// ---------------------------------------------------------------------------
extern "C" void kernel_launch(void* const* d_in, const int* in_sizes, int n_in,
                              void* d_out, int out_size, void* d_ws, size_t ws_size,
                              hipStream_t stream)
{
    const float2* inp = (const float2*)d_in[0];
    const float* W1 = (const float*)d_in[1];
    const float* b1 = (const float*)d_in[2];
    const float* W2 = (const float*)d_in[3];
    const float* b2 = (const float*)d_in[4];
    const float* W3 = (const float*)d_in[5];
    const float* b3 = (const float*)d_in[6];
    float* out = (float*)d_out;

    const int B = in_sizes[0] / 2;          // 262144
    const int nsteps = out_size / B;        // 40

    float2*   st0 = (float2*)d_ws;
    float2*   st1 = st0 + B;
    unsigned* cnt0 = (unsigned*)(st1 + B);
    unsigned* cnt1 = cnt0 + NCHUNK;
    u64*      msk0 = (u64*)(cnt1 + NCHUNK);
    u64*      msk1 = msk0 + (B / 64);

    // step 0: no pull
    fused_kernel<<<NBLK, NTHR, 0, stream>>>(inp, W1, b1, W2, b2, W3, b3,
                                            st0, cnt0, msk0,
                                            st0, cnt0, msk0, nullptr, 0);
    // steps 1..nsteps-1: pull prev (writes traj row t-1) + compute step t
    for (int t = 1; t < nsteps; ++t) {
        const bool odd = (t & 1);
        const float2*   stP  = odd ? st0  : st1;
        const unsigned* cntP = odd ? cnt0 : cnt1;
        const u64*      mskP = odd ? msk0 : msk1;
        float2*   stN  = odd ? st1  : st0;
        unsigned* cntN = odd ? cnt1 : cnt0;
        u64*      mskN = odd ? msk1 : msk0;
        fused_kernel<<<NBLK, NTHR, 0, stream>>>(inp, W1, b1, W2, b2, W3, b3,
                                                stP, cntP, mskP,
                                                stN, cntN, mskN,
                                                out + (size_t)(t - 1) * B, 1);
    }
    // final pull-only: traj row nsteps-1
    {
        const bool odd = (nsteps & 1);
        const float2*   stP  = odd ? st0  : st1;
        const unsigned* cntP = odd ? cnt0 : cnt1;
        const u64*      mskP = odd ? msk0 : msk1;
        fused_kernel<<<NBLK, NTHR, 0, stream>>>(inp, W1, b1, W2, b2, W3, b3,
                                                stP, cntP, mskP,
                                                st0, cnt0, msk0,
                                                out + (size_t)(nsteps - 1) * B, 2);
    }
}